// Round 1
// baseline (3576.970 us; speedup 1.0000x reference)
//
#include <hip/hip_runtime.h>
#include <math.h>

#define P_TOT 8192
#define CDIM  256
#define KC    50
#define NPIX  1024
#define TI    32
#define JS    2
#define NJT   256   // 8192 / 32 j-tiles
#define PAD   257

// workspace float offsets
#define OFF_NRM   0         // [8192]  clamped row norms
#define OFF_Z     8192      // [8192]  sum exp(s-1) per ano row
#define OFF_S2    16384     // [8192]  sum exp^2
#define OFF_THR   24576     // [8192]  thr per ano row
#define OFF_DEN   32768     // [8192]  sum sw per ano row
#define OFF_C2    40960     // [64]    center row norms^2
#define OFF_SCAL  41024     // [64]    0=sum_d_nor 1=sum_d_ano
#define OFF_CT    41088     // [12800] centerT [c][k]
#define OFF_XN    65536     // [2097152] normalized features row-major [P][C]
#define OFF_OUT   2162688   // [2097152] accumulated new_vals numerator
#define IOFF_BASE 4259840   // int region starts here (in float units)
// int offsets within int region
#define II_ANOIDX 0      // [8192]
#define II_M      8192
#define II_CNTANO 8193
#define II_FLAGS  8200   // [8192]

__global__ void k0_prep(const float* __restrict__ center, float* __restrict__ wsF) {
    int tid = threadIdx.x;
    float* cT = wsF + OFF_CT;
    float* c2 = wsF + OFF_C2;
    for (int idx = tid; idx < KC * CDIM; idx += 256) {
        int k = idx / CDIM, c = idx % CDIM;
        cT[c * KC + k] = center[idx];
    }
    if (tid < KC) {
        float s = 0.f;
        for (int c = 0; c < CDIM; ++c) { float v = center[tid * CDIM + c]; s += v * v; }
        c2[tid] = s;
    }
}

__global__ __launch_bounds__(256) void k1_dist(const float* __restrict__ f,
                                               const float* __restrict__ TcP,
                                               float* __restrict__ wsF,
                                               int* __restrict__ wsI) {
    __shared__ float sCT[CDIM * KC];
    __shared__ float sC2[KC];
    int tid = threadIdx.x;
    for (int idx = tid; idx < CDIM * KC; idx += 256) sCT[idx] = wsF[OFF_CT + idx];
    if (tid < KC) sC2[tid] = wsF[OFF_C2 + tid];
    __syncthreads();

    int p = blockIdx.x * 256 + tid;
    int b = p >> 10, n = p & 1023;
    const float* fp = f + (size_t)b * CDIM * NPIX + n;

    float acc[KC];
#pragma unroll
    for (int k = 0; k < KC; ++k) acc[k] = 0.f;
    float x2 = 0.f;
    for (int c = 0; c < CDIM; ++c) {
        float xv = fp[(size_t)c * NPIX];
        x2 += xv * xv;
        const float* ct = &sCT[c * KC];
#pragma unroll
        for (int k = 0; k < KC; ++k) acc[k] += xv * ct[k];
    }
    float d2m = 3.4e38f;
#pragma unroll
    for (int k = 0; k < KC; ++k) {
        float d2 = x2 + sC2[k] - 2.f * acc[k];
        d2m = fminf(d2m, d2);
    }
    float d = sqrtf(fmaxf(d2m, 0.f));
    bool ano = d > TcP[0];
    wsF[OFF_NRM + p] = fmaxf(sqrtf(x2), 1e-8f);
    wsI[II_FLAGS + p] = ano ? 1 : 0;

    // wave reductions for Ld sums
    float dn = ano ? 0.f : d;
    float da = ano ? d : 0.f;
    for (int o = 32; o >= 1; o >>= 1) { dn += __shfl_down(dn, o); da += __shfl_down(da, o); }
    int lane = tid & 63;
    unsigned long long mask = __ballot(ano);
    int cnt = __popcll(mask);
    if (lane == 0) {
        atomicAdd(&wsF[OFF_SCAL + 0], dn);
        atomicAdd(&wsF[OFF_SCAL + 1], da);
        if (cnt) atomicAdd(&wsI[II_CNTANO], cnt);
    }
    if (ano) {
        int leader = __ffsll((unsigned long long)mask) - 1;
        int base = 0;
        if (lane == leader) base = atomicAdd(&wsI[II_M], cnt);
        base = __shfl(base, leader);
        int off = __popcll(mask & ((1ull << lane) - 1ull));
        wsI[II_ANOIDX + base + off] = p;
    }
}

__global__ void k2_transpose(const float* __restrict__ f, float* __restrict__ wsF) {
    __shared__ float t[32][33];
    int b = blockIdx.z, n0 = blockIdx.x * 32, c0 = blockIdx.y * 32;
    int tx = threadIdx.x, ty = threadIdx.y;
    const float* src = f + ((size_t)b * CDIM + c0) * NPIX + n0;
#pragma unroll
    for (int r = 0; r < 32; r += 8) t[ty + r][tx] = src[(size_t)(ty + r) * NPIX + tx];
    __syncthreads();
    float* Xn = wsF + OFF_XN;
#pragma unroll
    for (int r = 0; r < 32; r += 8) {
        int n = n0 + ty + r;
        int p = b * NPIX + n;
        float nrm = wsF[OFF_NRM + p];
        Xn[(size_t)p * CDIM + c0 + tx] = t[tx][ty + r] / nrm;
    }
}

__global__ void k3_copy(const float* __restrict__ f, float* __restrict__ out,
                        const float* __restrict__ wsF, const int* __restrict__ wsI) {
    int gid = blockIdx.x * blockDim.x + threadIdx.x;
    const float4* src = (const float4*)f;
    float4* dst = (float4*)out;
    int total = P_TOT * CDIM / 4;
    for (int i = gid; i < total; i += gridDim.x * blockDim.x) dst[i] = src[i];
    if (gid == 0) {
        int cntAno = wsI[II_CNTANO];
        float cntNor = (float)(P_TOT - cntAno);
        float meanNor = wsF[OFF_SCAL + 0] / fmaxf(cntNor, 1.f);
        float meanAno = wsF[OFF_SCAL + 1] / fmaxf((float)cntAno, 1.f);
        out[P_TOT * CDIM] = (cntAno > 0) ? meanNor / (meanAno + 0.001f) : meanNor;
    }
}

__global__ __launch_bounds__(256) void k4a_pass1(float* __restrict__ wsF, const int* __restrict__ wsI) {
    const int Mv = wsI[II_M];
    int i0 = blockIdx.x * TI;
    if (i0 >= Mv) return;
    __shared__ float sA[TI][PAD];
    __shared__ float sB[TI][PAD];
    __shared__ int sRow[TI];
    __shared__ int sFlag[TI];
    int tid = threadIdx.x;
    const int* anoIdx = wsI + II_ANOIDX;
    const int* flags = wsI + II_FLAGS;
    const float* Xn = wsF + OFF_XN;

    if (tid < TI) sRow[tid] = anoIdx[min(i0 + tid, Mv - 1)];
    __syncthreads();
    for (int v = tid; v < TI * 64; v += 256) {
        int r = v >> 6, c4 = (v & 63) * 4;
        float4 val = *(const float4*)&Xn[(size_t)sRow[r] * CDIM + c4];
        sA[r][c4] = val.x; sA[r][c4 + 1] = val.y; sA[r][c4 + 2] = val.z; sA[r][c4 + 3] = val.w;
    }

    int ty = tid >> 4, tx = tid & 15;
    float zAcc0 = 0.f, zAcc1 = 0.f, s2Acc0 = 0.f, s2Acc1 = 0.f;
    int jt0 = blockIdx.y * (NJT / JS), jt1 = jt0 + NJT / JS;
    for (int jt = jt0; jt < jt1; ++jt) {
        int j0 = jt * TI;
        __syncthreads();
        for (int v = tid; v < TI * 64; v += 256) {
            int r = v >> 6, c4 = (v & 63) * 4;
            float4 val = *(const float4*)&Xn[(size_t)(j0 + r) * CDIM + c4];
            sB[r][c4] = val.x; sB[r][c4 + 1] = val.y; sB[r][c4 + 2] = val.z; sB[r][c4 + 3] = val.w;
        }
        if (tid < TI) sFlag[tid] = flags[j0 + tid];
        __syncthreads();

        const float* a0 = sA[2 * ty];
        const float* a1 = sA[2 * ty + 1];
        const float* b0 = sB[2 * tx];
        const float* b1 = sB[2 * tx + 1];
        float s00 = 0.f, s01 = 0.f, s10 = 0.f, s11 = 0.f;
#pragma unroll 8
        for (int c = 0; c < CDIM; ++c) {
            float av0 = a0[c], av1 = a1[c], bv0 = b0[c], bv1 = b1[c];
            s00 += av0 * bv0; s01 += av0 * bv1; s10 += av1 * bv0; s11 += av1 * bv1;
        }
        int m0 = sFlag[2 * tx], m1 = sFlag[2 * tx + 1];
        float e00 = m0 ? 0.f : expf(s00 - 1.f);
        float e01 = m1 ? 0.f : expf(s01 - 1.f);
        float e10 = m0 ? 0.f : expf(s10 - 1.f);
        float e11 = m1 ? 0.f : expf(s11 - 1.f);
        float z0 = e00 + e01, z1 = e10 + e11;
        float q0 = e00 * e00 + e01 * e01, q1 = e10 * e10 + e11 * e11;
        for (int o = 8; o >= 1; o >>= 1) {
            z0 += __shfl_xor(z0, o); z1 += __shfl_xor(z1, o);
            q0 += __shfl_xor(q0, o); q1 += __shfl_xor(q1, o);
        }
        zAcc0 += z0; zAcc1 += z1; s2Acc0 += q0; s2Acc1 += q1;
    }
    if (tx == 0) {
        int i = i0 + 2 * ty;
        if (i < Mv)     { atomicAdd(&wsF[OFF_Z + i], zAcc0);     atomicAdd(&wsF[OFF_S2 + i], s2Acc0); }
        if (i + 1 < Mv) { atomicAdd(&wsF[OFF_Z + i + 1], zAcc1); atomicAdd(&wsF[OFF_S2 + i + 1], s2Acc1); }
    }
}

__global__ void k4b_thr(float* __restrict__ wsF, const int* __restrict__ wsI) {
    int Mv = wsI[II_M];
    int idx = blockIdx.x * 256 + threadIdx.x;
    if (idx >= Mv) return;
    float t = fmaxf((float)(P_TOT - wsI[II_CNTANO]), 1.f);
    float Z = wsF[OFF_Z + idx], S2 = wsF[OFF_S2 + idx];
    float mu = 1.f / t;
    float var = S2 / (Z * Z * t) - mu * mu;
    wsF[OFF_THR + idx] = mu - 2.f * sqrtf(fmaxf(var, 0.f));
}

__global__ __launch_bounds__(256) void k4c_pass2(float* __restrict__ wsF, const int* __restrict__ wsI) {
    const int Mv = wsI[II_M];
    int i0 = blockIdx.x * TI;
    if (i0 >= Mv) return;
    __shared__ float sA[TI][PAD];
    __shared__ float sB[TI][PAD];
    __shared__ float sSW[TI][TI + 1];
    __shared__ float sNrm[TI];
    __shared__ int sRow[TI];
    __shared__ int sFlag[TI];
    __shared__ float sZ[TI], sThr[TI];
    int tid = threadIdx.x;
    const int* anoIdx = wsI + II_ANOIDX;
    const int* flags = wsI + II_FLAGS;
    const float* Xn = wsF + OFF_XN;

    if (tid < TI) {
        int i = min(i0 + tid, Mv - 1);
        sRow[tid] = anoIdx[i];
        sZ[tid] = wsF[OFF_Z + i];
        sThr[tid] = wsF[OFF_THR + i];
    }
    __syncthreads();
    for (int v = tid; v < TI * 64; v += 256) {
        int r = v >> 6, c4 = (v & 63) * 4;
        float4 val = *(const float4*)&Xn[(size_t)sRow[r] * CDIM + c4];
        sA[r][c4] = val.x; sA[r][c4 + 1] = val.y; sA[r][c4 + 2] = val.z; sA[r][c4 + 3] = val.w;
    }

    int ty = tid >> 4, tx = tid & 15;
    float rz0 = 1.f / sZ[2 * ty], rz1 = 1.f / sZ[2 * ty + 1];
    float thr0 = sThr[2 * ty], thr1 = sThr[2 * ty + 1];
    float den0 = 0.f, den1 = 0.f;
    int ii = tid >> 3, cg = tid & 7;
    float accO[32];
#pragma unroll
    for (int cc = 0; cc < 32; ++cc) accO[cc] = 0.f;

    int jt0 = blockIdx.y * (NJT / JS), jt1 = jt0 + NJT / JS;
    for (int jt = jt0; jt < jt1; ++jt) {
        int j0 = jt * TI;
        __syncthreads();
        for (int v = tid; v < TI * 64; v += 256) {
            int r = v >> 6, c4 = (v & 63) * 4;
            float4 val = *(const float4*)&Xn[(size_t)(j0 + r) * CDIM + c4];
            sB[r][c4] = val.x; sB[r][c4 + 1] = val.y; sB[r][c4 + 2] = val.z; sB[r][c4 + 3] = val.w;
        }
        if (tid < TI) {
            sFlag[tid] = flags[j0 + tid];
            sNrm[tid] = wsF[OFF_NRM + j0 + tid];
        }
        __syncthreads();

        const float* a0 = sA[2 * ty];
        const float* a1 = sA[2 * ty + 1];
        const float* b0 = sB[2 * tx];
        const float* b1 = sB[2 * tx + 1];
        float s00 = 0.f, s01 = 0.f, s10 = 0.f, s11 = 0.f;
#pragma unroll 8
        for (int c = 0; c < CDIM; ++c) {
            float av0 = a0[c], av1 = a1[c], bv0 = b0[c], bv1 = b1[c];
            s00 += av0 * bv0; s01 += av0 * bv1; s10 += av1 * bv0; s11 += av1 * bv1;
        }
        int m0 = sFlag[2 * tx], m1 = sFlag[2 * tx + 1];
        float w00 = m0 ? 0.f : expf(s00 - 1.f) * rz0;
        float w01 = m1 ? 0.f : expf(s01 - 1.f) * rz0;
        float w10 = m0 ? 0.f : expf(s10 - 1.f) * rz1;
        float w11 = m1 ? 0.f : expf(s11 - 1.f) * rz1;
        float d00 = w00 - thr0, d01 = w01 - thr0, d10 = w10 - thr1, d11 = w11 - thr1;
        float sw00 = fmaxf(d00, 0.f) * w00 / (fabsf(d00) + 1e-10f);
        float sw01 = fmaxf(d01, 0.f) * w01 / (fabsf(d01) + 1e-10f);
        float sw10 = fmaxf(d10, 0.f) * w10 / (fabsf(d10) + 1e-10f);
        float sw11 = fmaxf(d11, 0.f) * w11 / (fabsf(d11) + 1e-10f);
        den0 += sw00 + sw01;
        den1 += sw10 + sw11;
        float nr0 = sNrm[2 * tx], nr1 = sNrm[2 * tx + 1];
        sSW[2 * ty][2 * tx] = sw00 * nr0;
        sSW[2 * ty][2 * tx + 1] = sw01 * nr1;
        sSW[2 * ty + 1][2 * tx] = sw10 * nr0;
        sSW[2 * ty + 1][2 * tx + 1] = sw11 * nr1;
        __syncthreads();

#pragma unroll 4
        for (int j = 0; j < TI; ++j) {
            float sval = sSW[ii][j];
            const float* brow = sB[j];
#pragma unroll
            for (int cc = 0; cc < 32; ++cc) accO[cc] += sval * brow[cc * 8 + cg];
        }
    }

    for (int o = 8; o >= 1; o >>= 1) { den0 += __shfl_xor(den0, o); den1 += __shfl_xor(den1, o); }
    if (tx == 0) {
        int i = i0 + 2 * ty;
        if (i < Mv)     atomicAdd(&wsF[OFF_DEN + i], den0);
        if (i + 1 < Mv) atomicAdd(&wsF[OFF_DEN + i + 1], den1);
    }
    if (i0 + ii < Mv) {
        float* go = wsF + OFF_OUT + (size_t)(i0 + ii) * CDIM;
#pragma unroll
        for (int cc = 0; cc < 32; ++cc) atomicAdd(&go[cc * 8 + cg], accO[cc]);
    }
}

__global__ void k4d_final(float* __restrict__ out, const float* __restrict__ wsF,
                          const int* __restrict__ wsI) {
    int Mv = wsI[II_M];
    int i0 = blockIdx.x * TI;
    if (i0 >= Mv) return;
    int tid = threadIdx.x;
    int ii = tid >> 3, cg = tid & 7;
    int i = i0 + ii;
    if (i >= Mv) return;
    int p = wsI[II_ANOIDX + i];
    int b = p >> 10, n = p & 1023;
    float rden = 1.f / wsF[OFF_DEN + i];
    const float* go = wsF + OFF_OUT + (size_t)i * CDIM;
    float* op = out + (size_t)b * CDIM * NPIX + n;
#pragma unroll
    for (int cc = 0; cc < 32; ++cc) {
        int c = cc * 8 + cg;
        op[(size_t)c * NPIX] = go[c] * rden;
    }
}

extern "C" void kernel_launch(void* const* d_in, const int* in_sizes, int n_in,
                              void* d_out, int out_size, void* d_ws, size_t ws_size,
                              hipStream_t stream) {
    const float* f = (const float*)d_in[0];
    const float* center = (const float*)d_in[1];
    const float* Tc = (const float*)d_in[2];
    float* out = (float*)d_out;
    float* wsF = (float*)d_ws;
    int* wsI = (int*)(wsF + IOFF_BASE);

    // zero accumulators (Z, S2, THR, DEN, C2 area, scalars), numerator, counters
    hipMemsetAsync(wsF + OFF_Z, 0, (41088 - OFF_Z) * sizeof(float), stream);
    hipMemsetAsync(wsF + OFF_OUT, 0, (size_t)P_TOT * CDIM * sizeof(float), stream);
    hipMemsetAsync(wsI + II_M, 0, 2 * sizeof(int), stream);

    k0_prep<<<1, 256, 0, stream>>>(center, wsF);
    k1_dist<<<32, 256, 0, stream>>>(f, Tc, wsF, wsI);
    dim3 g2(32, 8, 8), b2(32, 8);
    k2_transpose<<<g2, b2, 0, stream>>>(f, wsF);
    k3_copy<<<512, 256, 0, stream>>>(f, out, wsF, wsI);
    dim3 g4(P_TOT / TI, JS);
    k4a_pass1<<<g4, 256, 0, stream>>>(wsF, wsI);
    k4b_thr<<<P_TOT / 256, 256, 0, stream>>>(wsF, wsI);
    k4c_pass2<<<g4, 256, 0, stream>>>(wsF, wsI);
    k4d_final<<<P_TOT / TI, 256, 0, stream>>>(out, wsF, wsI);
}

// Round 2
// 238.054 us; speedup vs baseline: 15.0259x; 15.0259x over previous
//
#include <hip/hip_runtime.h>
#include <math.h>

#define P_TOT 8192
#define CDIM  256
#define KC    50
#define NPIX  1024
#define TI    32

// MFMA pass geometry
#define RPB   128            // ano rows per block (4 waves x 32)
#define JSP   8              // j splits across blocks
#define JCH   (P_TOT / JSP)  // 1024 cols per block
#define JST   64             // j step (staged tile cols)

// workspace float offsets
#define OFF_NRM   0         // [8192]
#define OFF_Z     8192      // [8192]
#define OFF_S2    16384     // [8192]
#define OFF_THR   24576     // [8192]
#define OFF_DEN   32768     // [8192]
#define OFF_SCAL  40960     // [64] 0=sum_d_nor 1=sum_d_ano
#define OFF_C2    41024     // [64]
#define OFF_CT    41088     // [12800]
#define OFF_XNB   65536     // [8192][256] bf16 normalized  (1M floats)
#define OFF_XTB   1114112   // [256][8192] bf16 raw X       (1M floats)
#define OFF_OUT   2162688   // [8192][256] f32 numerator accum
#define IOFF_BASE 4259840
#define II_ANOIDX 0
#define II_M      8192
#define II_CNTANO 8193
#define II_FLAGS  8200

typedef __attribute__((ext_vector_type(8))) short short8;
typedef __attribute__((ext_vector_type(4))) float f32x4;

__device__ __forceinline__ ushort f2bf(float x) {
    union { float f; unsigned u; } v; v.f = x;
    unsigned r = v.u + 0x7fffu + ((v.u >> 16) & 1u);
    return (ushort)(r >> 16);
}
__device__ __forceinline__ float bf2f(ushort h) {
    union { unsigned u; float f; } v; v.u = ((unsigned)h) << 16;
    return v.f;
}

__global__ void k0_prep(const float* __restrict__ center, float* __restrict__ wsF) {
    int tid = threadIdx.x;
    float* cT = wsF + OFF_CT;
    float* c2 = wsF + OFF_C2;
    for (int idx = tid; idx < KC * CDIM; idx += 256) {
        int k = idx / CDIM, c = idx % CDIM;
        cT[c * KC + k] = center[idx];
    }
    if (tid < KC) {
        float s = 0.f;
        for (int c = 0; c < CDIM; ++c) { float v = center[tid * CDIM + c]; s += v * v; }
        c2[tid] = s;
    }
}

__global__ __launch_bounds__(256) void k1_dist(const float* __restrict__ f,
                                               const float* __restrict__ TcP,
                                               float* __restrict__ wsF,
                                               int* __restrict__ wsI) {
    __shared__ float sCT[CDIM * KC];
    __shared__ float sC2[KC];
    int tid = threadIdx.x;
    for (int idx = tid; idx < CDIM * KC; idx += 256) sCT[idx] = wsF[OFF_CT + idx];
    if (tid < KC) sC2[tid] = wsF[OFF_C2 + tid];
    __syncthreads();

    int p = blockIdx.x * 256 + tid;
    int b = p >> 10, n = p & 1023;
    const float* fp = f + (size_t)b * CDIM * NPIX + n;

    float acc[KC];
#pragma unroll
    for (int k = 0; k < KC; ++k) acc[k] = 0.f;
    float x2 = 0.f;
    for (int c = 0; c < CDIM; ++c) {
        float xv = fp[(size_t)c * NPIX];
        x2 += xv * xv;
        const float* ct = &sCT[c * KC];
#pragma unroll
        for (int k = 0; k < KC; ++k) acc[k] += xv * ct[k];
    }
    float d2m = 3.4e38f;
#pragma unroll
    for (int k = 0; k < KC; ++k) {
        float d2 = x2 + sC2[k] - 2.f * acc[k];
        d2m = fminf(d2m, d2);
    }
    float d = sqrtf(fmaxf(d2m, 0.f));
    bool ano = d > TcP[0];
    wsF[OFF_NRM + p] = fmaxf(sqrtf(x2), 1e-8f);
    wsI[II_FLAGS + p] = ano ? 1 : 0;

    float dn = ano ? 0.f : d;
    float da = ano ? d : 0.f;
    for (int o = 32; o >= 1; o >>= 1) { dn += __shfl_down(dn, o); da += __shfl_down(da, o); }
    int lane = tid & 63;
    unsigned long long mask = __ballot(ano);
    int cnt = __popcll(mask);
    if (lane == 0) {
        atomicAdd(&wsF[OFF_SCAL + 0], dn);
        atomicAdd(&wsF[OFF_SCAL + 1], da);
        if (cnt) atomicAdd(&wsI[II_CNTANO], cnt);
    }
    if (ano) {
        int leader = __ffsll((unsigned long long)mask) - 1;
        int base = 0;
        if (lane == leader) base = atomicAdd(&wsI[II_M], cnt);
        base = __shfl(base, leader);
        int off = __popcll(mask & ((1ull << lane) - 1ull));
        wsI[II_ANOIDX + base + off] = p;
    }
}

// f [b][c][n] fp32 -> XnB [p][c] bf16 normalized, XTB [c][p] bf16 raw
__global__ void k2_convert(const float* __restrict__ f, float* __restrict__ wsF) {
    __shared__ float t[32][33];
    int b = blockIdx.z, n0 = blockIdx.x * 32, c0 = blockIdx.y * 32;
    int tx = threadIdx.x, ty = threadIdx.y;
    const float* src = f + ((size_t)b * CDIM + c0) * NPIX + n0;
    ushort* XnB = (ushort*)(wsF + OFF_XNB);
    ushort* XTB = (ushort*)(wsF + OFF_XTB);
#pragma unroll
    for (int r = 0; r < 32; r += 8) {
        float v = src[(size_t)(ty + r) * NPIX + tx];
        t[ty + r][tx] = v;
        XTB[(size_t)(c0 + ty + r) * P_TOT + b * NPIX + n0 + tx] = f2bf(v);
    }
    __syncthreads();
#pragma unroll
    for (int r = 0; r < 32; r += 8) {
        int p = b * NPIX + n0 + ty + r;
        float nrm = wsF[OFF_NRM + p];
        XnB[(size_t)p * CDIM + c0 + tx] = f2bf(t[tx][ty + r] / nrm);
    }
}

__global__ void k3_copy(const float* __restrict__ f, float* __restrict__ out,
                        const float* __restrict__ wsF, const int* __restrict__ wsI) {
    int gid = blockIdx.x * blockDim.x + threadIdx.x;
    const float4* src = (const float4*)f;
    float4* dst = (float4*)out;
    int total = P_TOT * CDIM / 4;
    for (int i = gid; i < total; i += gridDim.x * blockDim.x) dst[i] = src[i];
    if (gid == 0) {
        int cntAno = wsI[II_CNTANO];
        float cntNor = (float)(P_TOT - cntAno);
        float meanNor = wsF[OFF_SCAL + 0] / fmaxf(cntNor, 1.f);
        float meanAno = wsF[OFF_SCAL + 1] / fmaxf((float)cntAno, 1.f);
        out[P_TOT * CDIM] = (cntAno > 0) ? meanNor / (meanAno + 0.001f) : meanNor;
    }
}

// pass1: Z = sum_nor exp(s-1), S2 = sum_nor exp^2  via MFMA
__global__ __launch_bounds__(256, 1) void k5a(float* __restrict__ wsF, const int* __restrict__ wsI) {
    const int Mv = wsI[II_M];
    const int i0 = blockIdx.x * RPB;
    if (i0 >= Mv) return;
    __shared__ __align__(16) ushort sK[64 * 256];
    __shared__ float sNor[JCH];
    const int tid = threadIdx.x;
    const int wave = tid >> 6, lane = tid & 63;
    const int lrow = lane & 15, lgrp = lane >> 4;
    const ushort* XnB = (const ushort*)(wsF + OFF_XNB);
    const int* flags = wsI + II_FLAGS;
    const int* anoIdx = wsI + II_ANOIDX;
    const int jc0 = blockIdx.y * JCH;

    for (int i = tid; i < JCH; i += 256) sNor[i] = flags[jc0 + i] ? 0.f : 1.f;

    const int iw = i0 + wave * 32;
    short8 qf[2][8];
#pragma unroll
    for (int t = 0; t < 2; ++t) {
        int ii = iw + t * 16 + lrow;
        int arow = anoIdx[min(ii, Mv - 1)];
        const ushort* qp = XnB + (size_t)arow * CDIM + lgrp * 8;
#pragma unroll
        for (int kc = 0; kc < 8; ++kc) qf[t][kc] = *(const short8*)(qp + kc * 32);
    }

    float zAcc[2][4], s2Acc[2][4];
#pragma unroll
    for (int t = 0; t < 2; ++t)
#pragma unroll
        for (int r = 0; r < 4; ++r) { zAcc[t][r] = 0.f; s2Acc[t][r] = 0.f; }

    for (int js = 0; js < JCH / JST; ++js) {
        int j0 = jc0 + js * JST;
        __syncthreads();
        const char* tile = (const char*)(XnB + (size_t)j0 * CDIM);
#pragma unroll
        for (int it = 0; it < 8; ++it) {
            int byte = (it * 256 + tid) << 4;
            int row = byte >> 9;
            int bir = byte & 511;
            int dst = (byte & ~511) | (bir ^ ((row & 7) << 4));
            *(int4*)((char*)sK + dst) = *(const int4*)(tile + byte);
        }
        __syncthreads();

        f32x4 acc[4][2];
#pragma unroll
        for (int tc = 0; tc < 4; ++tc)
#pragma unroll
            for (int t = 0; t < 2; ++t) acc[tc][t] = (f32x4){0.f, 0.f, 0.f, 0.f};

#pragma unroll
        for (int kc = 0; kc < 8; ++kc) {
            int cb = kc * 64 + lgrp * 16;
#pragma unroll
            for (int tc = 0; tc < 4; ++tc) {
                int brow = tc * 16 + lrow;
                int bo = brow * 512 + (cb ^ ((brow & 7) << 4));
                short8 bf = *(const short8*)((const char*)sK + bo);
                acc[tc][0] = __builtin_amdgcn_mfma_f32_16x16x32_bf16(qf[0][kc], bf, acc[tc][0], 0, 0, 0);
                acc[tc][1] = __builtin_amdgcn_mfma_f32_16x16x32_bf16(qf[1][kc], bf, acc[tc][1], 0, 0, 0);
            }
        }
#pragma unroll
        for (int tc = 0; tc < 4; ++tc) {
            float mflag = sNor[js * JST + tc * 16 + lrow];
#pragma unroll
            for (int r = 0; r < 4; ++r) {
                float e0 = __expf(acc[tc][0][r] - 1.f) * mflag;
                float e1 = __expf(acc[tc][1][r] - 1.f) * mflag;
                zAcc[0][r] += e0; s2Acc[0][r] += e0 * e0;
                zAcc[1][r] += e1; s2Acc[1][r] += e1 * e1;
            }
        }
    }
#pragma unroll
    for (int t = 0; t < 2; ++t)
#pragma unroll
        for (int r = 0; r < 4; ++r) {
            float z = zAcc[t][r], q = s2Acc[t][r];
            for (int m = 8; m >= 1; m >>= 1) { z += __shfl_xor(z, m); q += __shfl_xor(q, m); }
            if (lrow == 0) {
                int i = iw + t * 16 + lgrp * 4 + r;
                if (i < Mv) { atomicAdd(&wsF[OFF_Z + i], z); atomicAdd(&wsF[OFF_S2 + i], q); }
            }
        }
}

__global__ void k4b_thr(float* __restrict__ wsF, const int* __restrict__ wsI) {
    int Mv = wsI[II_M];
    int idx = blockIdx.x * 256 + threadIdx.x;
    if (idx >= Mv) return;
    float t = fmaxf((float)(P_TOT - wsI[II_CNTANO]), 1.f);
    float Z = wsF[OFF_Z + idx], S2 = wsF[OFF_S2 + idx];
    float mu = 1.f / t;
    float var = S2 / (Z * Z * t) - mu * mu;
    wsF[OFF_THR + idx] = mu - 2.f * sqrtf(fmaxf(var, 0.f));
}

// pass2: sim via MFMA -> sw -> (sw @ X) via MFMA, accumulate numerator + den
__global__ __launch_bounds__(256, 1) void k5c(float* __restrict__ wsF, const int* __restrict__ wsI) {
    const int Mv = wsI[II_M];
    const int i0 = blockIdx.x * RPB;
    if (i0 >= Mv) return;
    __shared__ __align__(16) ushort sK[64 * 256];
    __shared__ __align__(16) ushort sXT[256 * 64];
    __shared__ __align__(16) ushort sSW[4][32 * 64];
    __shared__ float sNor[JCH];
    const int tid = threadIdx.x;
    const int wave = tid >> 6, lane = tid & 63;
    const int lrow = lane & 15, lgrp = lane >> 4;
    const ushort* XnB = (const ushort*)(wsF + OFF_XNB);
    const ushort* XTB = (const ushort*)(wsF + OFF_XTB);
    const int* flags = wsI + II_FLAGS;
    const int* anoIdx = wsI + II_ANOIDX;
    const int jc0 = blockIdx.y * JCH;

    for (int i = tid; i < JCH; i += 256) sNor[i] = flags[jc0 + i] ? 0.f : 1.f;

    const int iw = i0 + wave * 32;
    short8 qf[2][8];
    float rz[2][4], thr[2][4], den[2][4];
#pragma unroll
    for (int t = 0; t < 2; ++t) {
        int ii = iw + t * 16 + lrow;
        int arow = anoIdx[min(ii, Mv - 1)];
        const ushort* qp = XnB + (size_t)arow * CDIM + lgrp * 8;
#pragma unroll
        for (int kc = 0; kc < 8; ++kc) qf[t][kc] = *(const short8*)(qp + kc * 32);
#pragma unroll
        for (int r = 0; r < 4; ++r) {
            int i = min(iw + t * 16 + lgrp * 4 + r, Mv - 1);
            rz[t][r] = 1.f / wsF[OFF_Z + i];
            thr[t][r] = wsF[OFF_THR + i];
            den[t][r] = 0.f;
        }
    }

    f32x4 oAcc[2][16];
#pragma unroll
    for (int t = 0; t < 2; ++t)
#pragma unroll
        for (int ct = 0; ct < 16; ++ct) oAcc[t][ct] = (f32x4){0.f, 0.f, 0.f, 0.f};

    ushort* mySW = sSW[wave];

    for (int js = 0; js < JCH / JST; ++js) {
        int j0 = jc0 + js * JST;
        __syncthreads();
        const char* tileK = (const char*)(XnB + (size_t)j0 * CDIM);
#pragma unroll
        for (int it = 0; it < 8; ++it) {
            int byte = (it * 256 + tid) << 4;
            int row = byte >> 9;
            int bir = byte & 511;
            int dst = (byte & ~511) | (bir ^ ((row & 7) << 4));
            *(int4*)((char*)sK + dst) = *(const int4*)(tileK + byte);
        }
#pragma unroll
        for (int it = 0; it < 8; ++it) {
            int byte = (it * 256 + tid) << 4;
            int row = byte >> 7;
            int bir = byte & 127;
            int dst = (byte & ~127) | (bir ^ ((row & 7) << 4));
            const char* src = (const char*)XTB + ((size_t)row * P_TOT + j0) * 2 + bir;
            *(int4*)((char*)sXT + dst) = *(const int4*)src;
        }
        __syncthreads();

        f32x4 acc[4][2];
#pragma unroll
        for (int tc = 0; tc < 4; ++tc)
#pragma unroll
            for (int t = 0; t < 2; ++t) acc[tc][t] = (f32x4){0.f, 0.f, 0.f, 0.f};

#pragma unroll
        for (int kc = 0; kc < 8; ++kc) {
            int cb = kc * 64 + lgrp * 16;
#pragma unroll
            for (int tc = 0; tc < 4; ++tc) {
                int brow = tc * 16 + lrow;
                int bo = brow * 512 + (cb ^ ((brow & 7) << 4));
                short8 bf = *(const short8*)((const char*)sK + bo);
                acc[tc][0] = __builtin_amdgcn_mfma_f32_16x16x32_bf16(qf[0][kc], bf, acc[tc][0], 0, 0, 0);
                acc[tc][1] = __builtin_amdgcn_mfma_f32_16x16x32_bf16(qf[1][kc], bf, acc[tc][1], 0, 0, 0);
            }
        }
        // sw into per-wave swizzled LDS tile
#pragma unroll
        for (int tc = 0; tc < 4; ++tc) {
            float mflag = sNor[js * JST + tc * 16 + lrow];
            int col2 = (tc * 16 + lrow) * 2;
#pragma unroll
            for (int t = 0; t < 2; ++t) {
#pragma unroll
                for (int r = 0; r < 4; ++r) {
                    float w = __expf(acc[tc][t][r] - 1.f) * mflag * rz[t][r];
                    float d = w - thr[t][r];
                    float sw = fmaxf(d, 0.f) * w / (fabsf(d) + 1e-10f);
                    ushort h = f2bf(sw);
                    den[t][r] += bf2f(h);
                    int row = t * 16 + lgrp * 4 + r;
                    int byteoff = (row * 128 + col2) ^ ((row & 7) << 4);
                    *(ushort*)((char*)mySW + byteoff) = h;
                }
            }
        }
        // PV: oAcc += sw_tile @ X_tile
#pragma unroll
        for (int kc2 = 0; kc2 < 2; ++kc2) {
            int cb = kc2 * 64 + lgrp * 16;
            int rx = (lrow & 7) << 4;
            short8 a0 = *(const short8*)((const char*)mySW + (lrow * 128 + (cb ^ rx)));
            short8 a1 = *(const short8*)((const char*)mySW + ((16 + lrow) * 128 + (cb ^ rx)));
#pragma unroll
            for (int ct = 0; ct < 16; ++ct) {
                int crow = ct * 16 + lrow;
                int bo = crow * 128 + (cb ^ ((crow & 7) << 4));
                short8 bf = *(const short8*)((const char*)sXT + bo);
                oAcc[0][ct] = __builtin_amdgcn_mfma_f32_16x16x32_bf16(a0, bf, oAcc[0][ct], 0, 0, 0);
                oAcc[1][ct] = __builtin_amdgcn_mfma_f32_16x16x32_bf16(a1, bf, oAcc[1][ct], 0, 0, 0);
            }
        }
    }

#pragma unroll
    for (int t = 0; t < 2; ++t)
#pragma unroll
        for (int r = 0; r < 4; ++r) {
            float dv = den[t][r];
            for (int m = 8; m >= 1; m >>= 1) dv += __shfl_xor(dv, m);
            if (lrow == 0) {
                int i = iw + t * 16 + lgrp * 4 + r;
                if (i < Mv) atomicAdd(&wsF[OFF_DEN + i], dv);
            }
        }
#pragma unroll
    for (int t = 0; t < 2; ++t) {
#pragma unroll
        for (int r = 0; r < 4; ++r) {
            int i = iw + t * 16 + lgrp * 4 + r;
            if (i < Mv) {
                float* go = wsF + OFF_OUT + (size_t)i * CDIM + lrow;
#pragma unroll
                for (int ct = 0; ct < 16; ++ct) atomicAdd(&go[ct * 16], oAcc[t][ct][r]);
            }
        }
    }
}

__global__ void k4d_final(float* __restrict__ out, const float* __restrict__ wsF,
                          const int* __restrict__ wsI) {
    int Mv = wsI[II_M];
    int i0 = blockIdx.x * TI;
    if (i0 >= Mv) return;
    int tid = threadIdx.x;
    int ii = tid >> 3, cg = tid & 7;
    int i = i0 + ii;
    if (i >= Mv) return;
    int p = wsI[II_ANOIDX + i];
    int b = p >> 10, n = p & 1023;
    float rden = 1.f / wsF[OFF_DEN + i];
    const float* go = wsF + OFF_OUT + (size_t)i * CDIM;
    float* op = out + (size_t)b * CDIM * NPIX + n;
#pragma unroll
    for (int cc = 0; cc < 32; ++cc) {
        int c = cc * 8 + cg;
        op[(size_t)c * NPIX] = go[c] * rden;
    }
}

extern "C" void kernel_launch(void* const* d_in, const int* in_sizes, int n_in,
                              void* d_out, int out_size, void* d_ws, size_t ws_size,
                              hipStream_t stream) {
    const float* f = (const float*)d_in[0];
    const float* center = (const float*)d_in[1];
    const float* Tc = (const float*)d_in[2];
    float* out = (float*)d_out;
    float* wsF = (float*)d_ws;
    int* wsI = (int*)(wsF + IOFF_BASE);

    hipMemsetAsync(wsF + OFF_Z, 0, (OFF_CT - OFF_Z) * sizeof(float), stream);
    hipMemsetAsync(wsF + OFF_OUT, 0, (size_t)P_TOT * CDIM * sizeof(float), stream);
    hipMemsetAsync(wsI + II_M, 0, 2 * sizeof(int), stream);

    k0_prep<<<1, 256, 0, stream>>>(center, wsF);
    k1_dist<<<32, 256, 0, stream>>>(f, Tc, wsF, wsI);
    dim3 g2(32, 8, 8), b2(32, 8);
    k2_convert<<<g2, b2, 0, stream>>>(f, wsF);
    k3_copy<<<512, 256, 0, stream>>>(f, out, wsF, wsI);
    dim3 g5(P_TOT / RPB, JSP);
    k5a<<<g5, 256, 0, stream>>>(wsF, wsI);
    k4b_thr<<<P_TOT / 256, 256, 0, stream>>>(wsF, wsI);
    k5c<<<g5, 256, 0, stream>>>(wsF, wsI);
    k4d_final<<<P_TOT / TI, 256, 0, stream>>>(out, wsF, wsI);
}